// Round 8
// baseline (280.790 us; speedup 1.0000x reference)
//
#include <hip/hip_runtime.h>
#include <cstdint>
#include <cstddef>

#define D_DIM   256
#define B_ROWS  1024
#define C_CLS   200000
#define S_SC    64.0f
#define COS_M_F 0.87758256189037271612f
#define SIN_M_F 0.47942553860420300027f
#define EPS_F   1e-8f

#define BM 256
#define BN 256
#define NT 782                     /* N-tiles: 782*256 = 200192 */
#define CPAD (NT * BN)             /* 200192 */
#define MT 4                       /* 1024/256 */
#define NBLK (MT * NT)             /* 3128 = 8*391, bijective XCD swizzle */

typedef int   i32x4  __attribute__((ext_vector_type(4)));
typedef int   i32x8  __attribute__((ext_vector_type(8)));
typedef float f32x16 __attribute__((ext_vector_type(16)));

// ---------------- kernel 1: normalize {proto, emb} -> fp8 e4m3 ----------------
__global__ void k_norm_all8(const float* __restrict__ emb,
                            const float* __restrict__ proto,
                            unsigned char* __restrict__ ebf8,
                            unsigned char* __restrict__ pbf8) {
  int wid = threadIdx.x >> 6, lane = threadIdx.x & 63;
  int idx = (blockIdx.x << 2) + wid;
  const float* src;
  unsigned char* dst;
  if (idx < CPAD) {
    if (idx >= C_CLS) {
      *reinterpret_cast<unsigned int*>(pbf8 + (size_t)idx * D_DIM + lane * 4) = 0u;
      return;
    }
    src = proto + (size_t)idx * D_DIM;
    dst = pbf8 + (size_t)idx * D_DIM;
  } else {
    int row = idx - CPAD;
    src = emb + (size_t)row * D_DIM;
    dst = ebf8 + (size_t)row * D_DIM;
  }
  const float4 v = *reinterpret_cast<const float4*>(src + lane * 4);
  float ss = v.x * v.x + v.y * v.y + v.z * v.z + v.w * v.w;
#pragma unroll
  for (int m = 32; m >= 1; m >>= 1) ss += __shfl_xor(ss, m, 64);
  float inv = 1.0f / fmaxf(sqrtf(ss), 1e-12f);
  int packed = 0;
  packed = __builtin_amdgcn_cvt_pk_fp8_f32(v.x * inv, v.y * inv, packed, false);
  packed = __builtin_amdgcn_cvt_pk_fp8_f32(v.z * inv, v.w * inv, packed, true);
  *reinterpret_cast<int*>(dst + lane * 4) = packed;
}

// ---------------- kernel 2: MX-fp8 GEMM (unit scales) + exp + row-sum ---------
// 256x256 tile, mfma_scale 32x32x64, 8 waves (2Mx4N, wave tile 128x64).
// A staged ONCE (64 KB); B triple-buffered (3x16 KB) with counted vmcnt.
__global__ __launch_bounds__(512, 2) void k_gemm_mx(
    const unsigned char* __restrict__ ebf8, const unsigned char* __restrict__ pbf8,
    float* __restrict__ sums) {
  __shared__ __align__(16) unsigned char Als[BM * 256];     // 64 KiB, row = 256 B
  __shared__ __align__(16) unsigned char Bls[3][BN * 64];   // 48 KiB, row = 64 B
  __shared__ float rowsum[BM];

  const int t = threadIdx.x;
  const int lane = t & 63;
  const int h = lane >> 5;          // k-half
  const int rsel = lane & 31;       // spatial index within 32
  const int wv = t >> 6;
  const int wm = wv >> 2;           // 0..1 : 128-row strip
  const int wn = wv & 3;            // 0..3 : 64-col strip

  int bid = (int)blockIdx.x;
  int w = (bid & 7) * (NBLK / 8) + (bid >> 3);   // bijective: NBLK = 8*391
  const int ntile = w >> 2;
  const int mtile = w & 3;
  const int m0 = mtile * BM;
  const int n0 = ntile * BN;

  // ---- prologue: stage whole A tile (256x256 B), granule XOR ^(r&15) ----
#pragma unroll
  for (int j = 0; j < 8; ++j) {
    int G = j * 512 + t;
    int r = G >> 4, p = G & 15;
    int lg = p ^ (r & 15);
    const unsigned char* g = ebf8 + (size_t)(m0 + r) * D_DIM + lg * 16;
    __builtin_amdgcn_global_load_lds(
        (const __attribute__((address_space(1))) unsigned int*)(const void*)g,
        (__attribute__((address_space(3))) unsigned int*)(void*)(Als + G * 16),
        16, 0, 0);
  }
  auto stageB = [&](int s, int kt) {   // one K-step slice: 256 rows x 64 B
#pragma unroll
    for (int j = 0; j < 2; ++j) {
      int G = j * 512 + t;
      int r = G >> 2, p = G & 3;
      int lg = p ^ (r & 3);
      const unsigned char* g = pbf8 + (size_t)(n0 + r) * D_DIM + kt * 64 + lg * 16;
      __builtin_amdgcn_global_load_lds(
          (const __attribute__((address_space(1))) unsigned int*)(const void*)g,
          (__attribute__((address_space(3))) unsigned int*)(void*)(Bls[s] + G * 16),
          16, 0, 0);
    }
  };
  stageB(0, 0);
  stageB(1, 1);
  if (t < BM) rowsum[t] = 0.0f;

  f32x16 acc[4][2];
#pragma unroll
  for (int mi = 0; mi < 4; ++mi)
#pragma unroll
    for (int ni = 0; ni < 2; ++ni)
#pragma unroll
      for (int e = 0; e < 16; ++e) acc[mi][ni][e] = 0.0f;

  asm volatile("s_waitcnt vmcnt(0)" ::: "memory");
  __builtin_amdgcn_s_barrier();
  __builtin_amdgcn_sched_barrier(0);

  auto STEP = [&](const unsigned char* Bbuf, int g0) {
    i32x8 af[4], bf[2];
#pragma unroll
    for (int ni = 0; ni < 2; ++ni) {
      int rb = wn * 64 + ni * 32 + rsel;
      int q0 = (h * 2) ^ (rb & 3), q1 = (h * 2 + 1) ^ (rb & 3);
      i32x4 lo = *reinterpret_cast<const i32x4*>(Bbuf + rb * 64 + q0 * 16);
      i32x4 hi = *reinterpret_cast<const i32x4*>(Bbuf + rb * 64 + q1 * 16);
      bf[ni] = __builtin_shufflevector(lo, hi, 0, 1, 2, 3, 4, 5, 6, 7);
    }
#pragma unroll
    for (int mi = 0; mi < 4; ++mi) {
      int ra = wm * 128 + mi * 32 + rsel;
      int p0 = (g0 + h * 2) ^ (ra & 15), p1 = (g0 + h * 2 + 1) ^ (ra & 15);
      i32x4 lo = *reinterpret_cast<const i32x4*>(Als + ra * 256 + p0 * 16);
      i32x4 hi = *reinterpret_cast<const i32x4*>(Als + ra * 256 + p1 * 16);
      af[mi] = __builtin_shufflevector(lo, hi, 0, 1, 2, 3, 4, 5, 6, 7);
    }
    __builtin_amdgcn_s_setprio(1);
#pragma unroll
    for (int mi = 0; mi < 4; ++mi)
#pragma unroll
      for (int ni = 0; ni < 2; ++ni)
        acc[mi][ni] = __builtin_amdgcn_mfma_scale_f32_32x32x64_f8f6f4(
            af[mi], bf[ni], acc[mi][ni], 0, 0,      // cbsz=fp8, blgp=fp8
            0, 0x7F7F7F7F, 0, 0x7F7F7F7F);          // unit scales (E8M0=127)
    __builtin_amdgcn_s_setprio(0);
  };

  // ---- 4 K-steps, counted-vmcnt pipeline ----
  stageB(2, 2);                 // flies under step 0
  STEP(Bls[0], 0);
  asm volatile("" ::: "memory");
  __builtin_amdgcn_s_barrier(); // release buf0 (buf1 ready since prologue)
  __builtin_amdgcn_sched_barrier(0);

  stageB(0, 3);                 // flies under step 1
  STEP(Bls[1], 4);
  asm volatile("s_waitcnt vmcnt(2)" ::: "memory");   // k2 landed; k3 in flight
  __builtin_amdgcn_s_barrier();
  __builtin_amdgcn_sched_barrier(0);

  STEP(Bls[2], 8);
  asm volatile("s_waitcnt vmcnt(0)" ::: "memory");   // k3 landed
  __builtin_amdgcn_s_barrier();
  __builtin_amdgcn_sched_barrier(0);

  STEP(Bls[0], 12);

  // ---- epilogue: exp -> per-row sums ----
  // C/D 32x32: row = (reg&3) + 8*(reg>>2) + 4*h ; col = rsel
  float vm[2];
  const int ccol = n0 + wn * 64 + rsel;
  vm[0] = (ccol < C_CLS) ? 1.0f : 0.0f;
  vm[1] = (ccol + 32 < C_CLS) ? 1.0f : 0.0f;
#pragma unroll
  for (int mi = 0; mi < 4; ++mi) {
#pragma unroll
    for (int rq = 0; rq < 4; ++rq) {
#pragma unroll
      for (int rr = 0; rr < 4; ++rr) {
        const int reg = rq * 4 + rr;
        float rs = vm[0] * __expf(S_SC * acc[mi][0][reg])
                 + vm[1] * __expf(S_SC * acc[mi][1][reg]);
        rs += __shfl_xor(rs, 1, 64);
        rs += __shfl_xor(rs, 2, 64);
        rs += __shfl_xor(rs, 4, 64);
        rs += __shfl_xor(rs, 8, 64);
        rs += __shfl_xor(rs, 16, 64);
        if (rsel == 0)
          atomicAdd(&rowsum[wm * 128 + mi * 32 + rr + 8 * rq + 4 * h], rs);
      }
    }
  }
  __syncthreads();
  if (t < BM) atomicAdd(&sums[m0 + t], rowsum[t]);
}

// ---------------- kernel 3: label column + final loss -------------------------
__device__ __forceinline__ float f8tof(unsigned char u) {
  int e = (u >> 3) & 15, m = u & 7;
  float mag = e ? ldexpf((float)(8 + m), e - 10) : ldexpf((float)m, -9);
  return (u & 0x80) ? -mag : mag;
}

__global__ void k_finalize(const unsigned char* __restrict__ ebf8,
                           const unsigned char* __restrict__ pbf8,
                           const int* __restrict__ labels,
                           const float* __restrict__ sums,
                           float* __restrict__ out) {
  __shared__ float part[4];
  int wid = threadIdx.x >> 6, lane = threadIdx.x & 63;
  int b = (blockIdx.x << 2) + wid;
  int lab = labels[b];
  const unsigned char* e = ebf8 + (size_t)b * D_DIM + lane * 4;
  const unsigned char* p = pbf8 + (size_t)lab * D_DIM + lane * 4;
  unsigned int eu = *reinterpret_cast<const unsigned int*>(e);
  unsigned int pu = *reinterpret_cast<const unsigned int*>(p);
  float dot = 0.0f;
#pragma unroll
  for (int i = 0; i < 4; ++i)
    dot += f8tof((eu >> (8 * i)) & 0xff) * f8tof((pu >> (8 * i)) & 0xff);
#pragma unroll
  for (int m = 32; m >= 1; m >>= 1) dot += __shfl_xor(dot, m, 64);
  if (lane == 0) {
    float cs = dot;
    float sn = sqrtf(fmaxf(1.0f - cs * cs, EPS_F));
    sn = fminf(fmaxf(sn, EPS_F), 1.0f - EPS_F);
    float phi = cs * COS_M_F - sn * SIN_M_F;
    float sp = S_SC * phi;
    float total = sums[b] - __expf(S_SC * cs) + __expf(sp);
    part[wid] = logf(total) - sp;
  }
  __syncthreads();
  if (threadIdx.x == 0) {
    float s = part[0] + part[1] + part[2] + part[3];
    atomicAdd(out, s * (1.0f / (float)B_ROWS));
  }
}

// ---------------- launcher ----------------------------------------------------
extern "C" void kernel_launch(void* const* d_in, const int* in_sizes, int n_in,
                              void* d_out, int out_size, void* d_ws, size_t ws_size,
                              hipStream_t stream) {
  const float* emb    = (const float*)d_in[0];
  const int*   labels = (const int*)d_in[1];
  const float* proto  = (const float*)d_in[2];
  float* out = (float*)d_out;

  char* ws = (char*)d_ws;
  unsigned char* ebf8 = (unsigned char*)ws;                 // 262144 B
  float* sums = (float*)(ws + 262144);                      // 4096 B
  unsigned char* pbf8 = (unsigned char*)(ws + 2097152);     // CPAD*256 = 51.2 MB

  hipMemsetAsync(sums, 0, B_ROWS * sizeof(float), stream);
  hipMemsetAsync(out, 0, sizeof(float), stream);

  k_norm_all8<<<(CPAD + B_ROWS) / 4, 256, 0, stream>>>(emb, proto, ebf8, pbf8);
  k_gemm_mx<<<NBLK, 512, 0, stream>>>(ebf8, pbf8, sums);
  k_finalize<<<B_ROWS / 4, 256, 0, stream>>>(ebf8, pbf8, labels, sums, out);
}

// Round 9
// 233.776 us; speedup vs baseline: 1.2011x; 1.2011x over previous
//
#include <hip/hip_runtime.h>
#include <cstdint>
#include <cstddef>

#define D_DIM   256
#define B_ROWS  1024
#define C_CLS   200000
#define S_SC    64.0f
#define COS_M_F 0.87758256189037271612f
#define SIN_M_F 0.47942553860420300027f
#define EPS_F   1e-8f

#define BM 128
#define BN 128
#define NT 1563                    /* N-tiles: 1563*128 = 200064 */
#define CPAD 200192                /* zero-padded pbf8 rows */
#define NBLK (8 * NT)              /* 12504 = 8*1563, bijective XCD swizzle */

typedef int   i32x4  __attribute__((ext_vector_type(4)));
typedef int   i32x8  __attribute__((ext_vector_type(8)));
typedef float f32x16 __attribute__((ext_vector_type(16)));

// ---------------- kernel 1: normalize {proto, emb} -> fp8 e4m3 ----------------
__global__ void k_norm_all8(const float* __restrict__ emb,
                            const float* __restrict__ proto,
                            unsigned char* __restrict__ ebf8,
                            unsigned char* __restrict__ pbf8) {
  int wid = threadIdx.x >> 6, lane = threadIdx.x & 63;
  int idx = (blockIdx.x << 2) + wid;
  const float* src;
  unsigned char* dst;
  if (idx < CPAD) {
    if (idx >= C_CLS) {
      *reinterpret_cast<unsigned int*>(pbf8 + (size_t)idx * D_DIM + lane * 4) = 0u;
      return;
    }
    src = proto + (size_t)idx * D_DIM;
    dst = pbf8 + (size_t)idx * D_DIM;
  } else {
    int row = idx - CPAD;
    src = emb + (size_t)row * D_DIM;
    dst = ebf8 + (size_t)row * D_DIM;
  }
  const float4 v = *reinterpret_cast<const float4*>(src + lane * 4);
  float ss = v.x * v.x + v.y * v.y + v.z * v.z + v.w * v.w;
#pragma unroll
  for (int m = 32; m >= 1; m >>= 1) ss += __shfl_xor(ss, m, 64);
  float inv = 1.0f / fmaxf(sqrtf(ss), 1e-12f);
  int packed = 0;
  packed = __builtin_amdgcn_cvt_pk_fp8_f32(v.x * inv, v.y * inv, packed, false);
  packed = __builtin_amdgcn_cvt_pk_fp8_f32(v.z * inv, v.w * inv, packed, true);
  *reinterpret_cast<int*>(dst + lane * 4) = packed;
}

// ---------------- kernel 2: MX-fp8 GEMM (unit scales) + exp + row-sum ---------
// R6's TLP skeleton (128x128 tile, 4 waves, ~33 KB LDS -> 4 blocks/CU, simple
// stage->sync->compute->sync) with R8-verified mfma_scale 32x32x64 math.
__global__ __launch_bounds__(256, 4) void k_gemm_mx(
    const unsigned char* __restrict__ ebf8, const unsigned char* __restrict__ pbf8,
    float* __restrict__ sums) {
  __shared__ __align__(16) unsigned char As[BM * 128];   // 16 KiB, row = 128 B
  __shared__ __align__(16) unsigned char Bs[BN * 128];   // 16 KiB
  __shared__ float rowsum[BM];

  const int t = threadIdx.x;
  const int lane = t & 63;
  const int h = lane >> 5;          // k-half
  const int rsel = lane & 31;       // spatial index within 32
  const int wv = t >> 6;
  const int wm = wv >> 1;           // 0..1 : 64-row strip
  const int wn = wv & 1;            // 0..1 : 64-col strip

  int bid = (int)blockIdx.x;
  int w = (bid & 7) * NT + (bid >> 3);   // bijective: NBLK = 8*NT
  const int ntile = w >> 3;
  const int mtile = w & 7;
  const int m0 = mtile * BM;
  const int n0 = ntile * BN;

  if (t < BM) rowsum[t] = 0.0f;

  f32x16 acc[2][2];
#pragma unroll
  for (int mi = 0; mi < 2; ++mi)
#pragma unroll
    for (int ni = 0; ni < 2; ++ni)
#pragma unroll
      for (int e = 0; e < 16; ++e) acc[mi][ni][e] = 0.0f;

  // stage one 128-B K-slice of A and B; dest linear granules, source
  // pre-swizzled so logical granule lg sits at phys p = lg ^ (r&7).
  auto stage = [&](int k0) {
#pragma unroll
    for (int j = 0; j < 4; ++j) {
      int G = j * 256 + t;          // 0..1023
      int r = G >> 3, p = G & 7;
      int lg = p ^ (r & 7);
      const unsigned char* gA = ebf8 + (size_t)(m0 + r) * D_DIM + k0 + lg * 16;
      __builtin_amdgcn_global_load_lds(
          (const __attribute__((address_space(1))) unsigned int*)(const void*)gA,
          (__attribute__((address_space(3))) unsigned int*)(void*)(As + G * 16),
          16, 0, 0);
      const unsigned char* gB = pbf8 + (size_t)(n0 + r) * D_DIM + k0 + lg * 16;
      __builtin_amdgcn_global_load_lds(
          (const __attribute__((address_space(1))) unsigned int*)(const void*)gB,
          (__attribute__((address_space(3))) unsigned int*)(void*)(Bs + G * 16),
          16, 0, 0);
    }
  };

  // read 32 B operand (logical granules e, e+1 of row r) from swizzled LDS;
  // address-side swizzle only: content k-order is lane-uniform (R8-verified).
  auto rd = [&](const unsigned char* buf, int r, int kc) -> i32x8 {
    int e = kc * 4 + h * 2;
    int p0 = e ^ (r & 7), p1 = (e + 1) ^ (r & 7);
    i32x4 lo = *reinterpret_cast<const i32x4*>(buf + r * 128 + p0 * 16);
    i32x4 hi = *reinterpret_cast<const i32x4*>(buf + r * 128 + p1 * 16);
    return __builtin_shufflevector(lo, hi, 0, 1, 2, 3, 4, 5, 6, 7);
  };

  auto STEP = [&]() {
#pragma unroll
    for (int kc = 0; kc < 2; ++kc) {   // 2 k-chunks of 64
      i32x8 af[2], bf[2];
#pragma unroll
      for (int mi = 0; mi < 2; ++mi)
        af[mi] = rd(As, wm * 64 + mi * 32 + rsel, kc);
#pragma unroll
      for (int ni = 0; ni < 2; ++ni)
        bf[ni] = rd(Bs, wn * 64 + ni * 32 + rsel, kc);
      __builtin_amdgcn_s_setprio(1);
#pragma unroll
      for (int mi = 0; mi < 2; ++mi)
#pragma unroll
        for (int ni = 0; ni < 2; ++ni)
          acc[mi][ni] = __builtin_amdgcn_mfma_scale_f32_32x32x64_f8f6f4(
              af[mi], bf[ni], acc[mi][ni], 0, 0,    // cbsz=fp8, blgp=fp8
              0, 0x7F7F7F7F, 0, 0x7F7F7F7F);        // unit scales (E8M0=127)
      __builtin_amdgcn_s_setprio(0);
    }
  };

  // ---- 2 K-steps, single buffer; 4 blocks/CU TLP hides the drains ----
  stage(0);
  __syncthreads();
  STEP();
  __syncthreads();
  stage(128);
  __syncthreads();
  STEP();

  // ---- epilogue: exp -> per-row sums ----
  // C/D 32x32 (R8-verified): row = (reg&3) + 8*(reg>>2) + 4*h ; col = rsel
  float vm[2];
  const int ccol = n0 + wn * 64 + rsel;
  vm[0] = (ccol < C_CLS) ? 1.0f : 0.0f;
  vm[1] = (ccol + 32 < C_CLS) ? 1.0f : 0.0f;
#pragma unroll
  for (int mi = 0; mi < 2; ++mi) {
#pragma unroll
    for (int rq = 0; rq < 4; ++rq) {
#pragma unroll
      for (int rr = 0; rr < 4; ++rr) {
        const int reg = rq * 4 + rr;
        float rs = vm[0] * __expf(S_SC * acc[mi][0][reg])
                 + vm[1] * __expf(S_SC * acc[mi][1][reg]);
        rs += __shfl_xor(rs, 1, 64);
        rs += __shfl_xor(rs, 2, 64);
        rs += __shfl_xor(rs, 4, 64);
        rs += __shfl_xor(rs, 8, 64);
        rs += __shfl_xor(rs, 16, 64);
        if (rsel == 0)
          atomicAdd(&rowsum[wm * 64 + mi * 32 + rr + 8 * rq + 4 * h], rs);
      }
    }
  }
  __syncthreads();
  if (t < BM) atomicAdd(&sums[m0 + t], rowsum[t]);
}

// ---------------- kernel 3: label column + final loss -------------------------
__device__ __forceinline__ float f8tof(unsigned char u) {
  int e = (u >> 3) & 15, m = u & 7;
  float mag = e ? ldexpf((float)(8 + m), e - 10) : ldexpf((float)m, -9);
  return (u & 0x80) ? -mag : mag;
}

__global__ void k_finalize(const unsigned char* __restrict__ ebf8,
                           const unsigned char* __restrict__ pbf8,
                           const int* __restrict__ labels,
                           const float* __restrict__ sums,
                           float* __restrict__ out) {
  __shared__ float part[4];
  int wid = threadIdx.x >> 6, lane = threadIdx.x & 63;
  int b = (blockIdx.x << 2) + wid;
  int lab = labels[b];
  const unsigned char* e = ebf8 + (size_t)b * D_DIM + lane * 4;
  const unsigned char* p = pbf8 + (size_t)lab * D_DIM + lane * 4;
  unsigned int eu = *reinterpret_cast<const unsigned int*>(e);
  unsigned int pu = *reinterpret_cast<const unsigned int*>(p);
  float dot = 0.0f;
#pragma unroll
  for (int i = 0; i < 4; ++i)
    dot += f8tof((eu >> (8 * i)) & 0xff) * f8tof((pu >> (8 * i)) & 0xff);
#pragma unroll
  for (int m = 32; m >= 1; m >>= 1) dot += __shfl_xor(dot, m, 64);
  if (lane == 0) {
    float cs = dot;
    float sn = sqrtf(fmaxf(1.0f - cs * cs, EPS_F));
    sn = fminf(fmaxf(sn, EPS_F), 1.0f - EPS_F);
    float phi = cs * COS_M_F - sn * SIN_M_F;
    float sp = S_SC * phi;
    float total = sums[b] - __expf(S_SC * cs) + __expf(sp);
    part[wid] = logf(total) - sp;
  }
  __syncthreads();
  if (threadIdx.x == 0) {
    float s = part[0] + part[1] + part[2] + part[3];
    atomicAdd(out, s * (1.0f / (float)B_ROWS));
  }
}

// ---------------- launcher ----------------------------------------------------
extern "C" void kernel_launch(void* const* d_in, const int* in_sizes, int n_in,
                              void* d_out, int out_size, void* d_ws, size_t ws_size,
                              hipStream_t stream) {
  const float* emb    = (const float*)d_in[0];
  const int*   labels = (const int*)d_in[1];
  const float* proto  = (const float*)d_in[2];
  float* out = (float*)d_out;

  char* ws = (char*)d_ws;
  unsigned char* ebf8 = (unsigned char*)ws;                 // 262144 B
  float* sums = (float*)(ws + 262144);                      // 4096 B
  unsigned char* pbf8 = (unsigned char*)(ws + 2097152);     // CPAD*256 = 51.2 MB

  hipMemsetAsync(sums, 0, B_ROWS * sizeof(float), stream);
  hipMemsetAsync(out, 0, sizeof(float), stream);

  k_norm_all8<<<(CPAD + B_ROWS) / 4, 256, 0, stream>>>(emb, proto, ebf8, pbf8);
  k_gemm_mx<<<NBLK, 256, 0, stream>>>(ebf8, pbf8, sums);
  k_finalize<<<B_ROWS / 4, 256, 0, stream>>>(ebf8, pbf8, labels, sums, out);
}

// Round 10
// 228.575 us; speedup vs baseline: 1.2284x; 1.0228x over previous
//
#include <hip/hip_runtime.h>
#include <cstdint>
#include <cstddef>

#define D_DIM   256
#define B_ROWS  1024
#define C_CLS   200000
#define S_SC    64.0f
#define COS_M_F 0.87758256189037271612f
#define SIN_M_F 0.47942553860420300027f
#define EPS_F   1e-8f

#define BM 128
#define BN 128
#define NT 1563                    /* N-tiles: 1563*128 = 200064 */
#define CPAD 200192                /* zero-padded pbf8 rows */
#define NBLK (8 * NT)              /* 12504 = 8*1563, bijective XCD swizzle */

typedef int   i32x4  __attribute__((ext_vector_type(4)));
typedef int   i32x8  __attribute__((ext_vector_type(8)));
typedef float f32x4  __attribute__((ext_vector_type(4)));

// ---------------- kernel 1: normalize {proto, emb} -> fp8 e4m3 ----------------
__global__ void k_norm_all8(const float* __restrict__ emb,
                            const float* __restrict__ proto,
                            unsigned char* __restrict__ ebf8,
                            unsigned char* __restrict__ pbf8) {
  int wid = threadIdx.x >> 6, lane = threadIdx.x & 63;
  int idx = (blockIdx.x << 2) + wid;
  const float* src;
  unsigned char* dst;
  if (idx < CPAD) {
    if (idx >= C_CLS) {
      *reinterpret_cast<unsigned int*>(pbf8 + (size_t)idx * D_DIM + lane * 4) = 0u;
      return;
    }
    src = proto + (size_t)idx * D_DIM;
    dst = pbf8 + (size_t)idx * D_DIM;
  } else {
    int row = idx - CPAD;
    src = emb + (size_t)row * D_DIM;
    dst = ebf8 + (size_t)row * D_DIM;
  }
  const float4 v = *reinterpret_cast<const float4*>(src + lane * 4);
  float ss = v.x * v.x + v.y * v.y + v.z * v.z + v.w * v.w;
#pragma unroll
  for (int m = 32; m >= 1; m >>= 1) ss += __shfl_xor(ss, m, 64);
  float inv = 1.0f / fmaxf(sqrtf(ss), 1e-12f);
  int packed = 0;
  packed = __builtin_amdgcn_cvt_pk_fp8_f32(v.x * inv, v.y * inv, packed, false);
  packed = __builtin_amdgcn_cvt_pk_fp8_f32(v.z * inv, v.w * inv, packed, true);
  *reinterpret_cast<int*>(dst + lane * 4) = packed;
}

// ---------------- kernel 2: register-direct MX-fp8 GEMM + exp + row-sum -------
// No staging LDS, no K-loop barriers: mfma_scale_f32_16x16x128 fragments are
// 32 contiguous bytes of one row -> loaded straight global->VGPR (L2/L3-hot).
// 128x128 tile, 4 waves (2x2, wave tile 64x64), 2 K-steps of 128.
__global__ __launch_bounds__(256, 2) void k_gemm_reg(
    const unsigned char* __restrict__ ebf8, const unsigned char* __restrict__ pbf8,
    float* __restrict__ sums) {
  __shared__ float rowsum[BM];

  const int t = threadIdx.x;
  const int lane = t & 63;
  const int rsel = lane & 15;       // row/col within 16
  const int kq = lane >> 4;         // k-quarter (32 B each)
  const int wv = t >> 6;
  const int wm = wv >> 1;           // 0..1 : 64-row strip
  const int wn = wv & 1;            // 0..1 : 64-col strip

  int bid = (int)blockIdx.x;
  int w = (bid & 7) * NT + (bid >> 3);   // bijective: NBLK = 8*NT
  const int ntile = w >> 3;
  const int mtile = w & 7;
  const int m0 = mtile * BM;
  const int n0 = ntile * BN;

  if (t < BM) rowsum[t] = 0.0f;

  // ---- A fragments (both K-steps) global->reg: 64 VGPR, L2-resident ----
  i32x8 Af[4][2];
#pragma unroll
  for (int mi = 0; mi < 4; ++mi) {
    const unsigned char* ab =
        ebf8 + (size_t)(m0 + wm * 64 + mi * 16 + rsel) * D_DIM + kq * 32;
#pragma unroll
    for (int ks = 0; ks < 2; ++ks) {
      i32x4 lo = *reinterpret_cast<const i32x4*>(ab + ks * 128);
      i32x4 hi = *reinterpret_cast<const i32x4*>(ab + ks * 128 + 16);
      Af[mi][ks] = __builtin_shufflevector(lo, hi, 0, 1, 2, 3, 4, 5, 6, 7);
    }
  }

  f32x4 acc[4][4];
  const f32x4 fz = {0.0f, 0.0f, 0.0f, 0.0f};
#pragma unroll
  for (int mi = 0; mi < 4; ++mi)
#pragma unroll
    for (int ni = 0; ni < 4; ++ni) acc[mi][ni] = fz;

  const unsigned char* bbase =
      pbf8 + (size_t)(n0 + wn * 64 + rsel) * D_DIM + kq * 32;

#pragma unroll
  for (int ks = 0; ks < 2; ++ks) {
    i32x8 Bf[4];
#pragma unroll
    for (int ni = 0; ni < 4; ++ni) {
      const unsigned char* bb = bbase + (size_t)ni * (16 * D_DIM) + ks * 128;
      i32x4 lo = *reinterpret_cast<const i32x4*>(bb);
      i32x4 hi = *reinterpret_cast<const i32x4*>(bb + 16);
      Bf[ni] = __builtin_shufflevector(lo, hi, 0, 1, 2, 3, 4, 5, 6, 7);
    }
#pragma unroll
    for (int mi = 0; mi < 4; ++mi)
#pragma unroll
      for (int ni = 0; ni < 4; ++ni)
        acc[mi][ni] = __builtin_amdgcn_mfma_scale_f32_16x16x128_f8f6f4(
            Af[mi][ks], Bf[ni], acc[mi][ni], 0, 0,   // cbsz=fp8, blgp=fp8
            0, 0x7F7F7F7F, 0, 0x7F7F7F7F);           // unit scales (E8M0=127)
  }

  __syncthreads();   // rowsum init visible before epilogue atomics

  // ---- epilogue: exp -> per-row sums ----
  // C/D 16x16 (shape-determined): row = kq*4 + reg ; col = rsel
  float vmask[4];
  const int ccol = n0 + wn * 64 + rsel;
#pragma unroll
  for (int ni = 0; ni < 4; ++ni)
    vmask[ni] = (ccol + ni * 16 < C_CLS) ? 1.0f : 0.0f;
#pragma unroll
  for (int mi = 0; mi < 4; ++mi) {
#pragma unroll
    for (int reg = 0; reg < 4; ++reg) {
      float rs = 0.0f;
#pragma unroll
      for (int ni = 0; ni < 4; ++ni)
        rs += vmask[ni] * __expf(S_SC * acc[mi][ni][reg]);
      rs += __shfl_xor(rs, 1, 64);
      rs += __shfl_xor(rs, 2, 64);
      rs += __shfl_xor(rs, 4, 64);
      rs += __shfl_xor(rs, 8, 64);
      if (rsel == 0)
        atomicAdd(&rowsum[wm * 64 + mi * 16 + kq * 4 + reg], rs);
    }
  }
  __syncthreads();
  if (t < BM) atomicAdd(&sums[m0 + t], rowsum[t]);
}

// ---------------- kernel 3: label column + final loss -------------------------
__device__ __forceinline__ float f8tof(unsigned char u) {
  int e = (u >> 3) & 15, m = u & 7;
  float mag = e ? ldexpf((float)(8 + m), e - 10) : ldexpf((float)m, -9);
  return (u & 0x80) ? -mag : mag;
}

__global__ void k_finalize(const unsigned char* __restrict__ ebf8,
                           const unsigned char* __restrict__ pbf8,
                           const int* __restrict__ labels,
                           const float* __restrict__ sums,
                           float* __restrict__ out) {
  __shared__ float part[4];
  int wid = threadIdx.x >> 6, lane = threadIdx.x & 63;
  int b = (blockIdx.x << 2) + wid;
  int lab = labels[b];
  const unsigned char* e = ebf8 + (size_t)b * D_DIM + lane * 4;
  const unsigned char* p = pbf8 + (size_t)lab * D_DIM + lane * 4;
  unsigned int eu = *reinterpret_cast<const unsigned int*>(e);
  unsigned int pu = *reinterpret_cast<const unsigned int*>(p);
  float dot = 0.0f;
#pragma unroll
  for (int i = 0; i < 4; ++i)
    dot += f8tof((eu >> (8 * i)) & 0xff) * f8tof((pu >> (8 * i)) & 0xff);
#pragma unroll
  for (int m = 32; m >= 1; m >>= 1) dot += __shfl_xor(dot, m, 64);
  if (lane == 0) {
    float cs = dot;
    float sn = sqrtf(fmaxf(1.0f - cs * cs, EPS_F));
    sn = fminf(fmaxf(sn, EPS_F), 1.0f - EPS_F);
    float phi = cs * COS_M_F - sn * SIN_M_F;
    float sp = S_SC * phi;
    float total = sums[b] - __expf(S_SC * cs) + __expf(sp);
    part[wid] = logf(total) - sp;
  }
  __syncthreads();
  if (threadIdx.x == 0) {
    float s = part[0] + part[1] + part[2] + part[3];
    atomicAdd(out, s * (1.0f / (float)B_ROWS));
  }
}

// ---------------- launcher ----------------------------------------------------
extern "C" void kernel_launch(void* const* d_in, const int* in_sizes, int n_in,
                              void* d_out, int out_size, void* d_ws, size_t ws_size,
                              hipStream_t stream) {
  const float* emb    = (const float*)d_in[0];
  const int*   labels = (const int*)d_in[1];
  const float* proto  = (const float*)d_in[2];
  float* out = (float*)d_out;

  char* ws = (char*)d_ws;
  unsigned char* ebf8 = (unsigned char*)ws;                 // 262144 B
  float* sums = (float*)(ws + 262144);                      // 4096 B
  unsigned char* pbf8 = (unsigned char*)(ws + 2097152);     // CPAD*256 = 51.2 MB

  hipMemsetAsync(sums, 0, B_ROWS * sizeof(float), stream);
  hipMemsetAsync(out, 0, sizeof(float), stream);

  k_norm_all8<<<(CPAD + B_ROWS) / 4, 256, 0, stream>>>(emb, proto, ebf8, pbf8);
  k_gemm_reg<<<NBLK, 256, 0, stream>>>(ebf8, pbf8, sums);
  k_finalize<<<B_ROWS / 4, 256, 0, stream>>>(ebf8, pbf8, labels, sums, out);
}

// Round 11
// 128.469 us; speedup vs baseline: 2.1857x; 1.7792x over previous
//
#include <hip/hip_runtime.h>
#include <cstdint>
#include <cstddef>

#define D_DIM   256
#define B_ROWS  1024
#define C_CLS   200000
#define S_SC    64.0f
#define COS_M_F 0.87758256189037271612f
#define SIN_M_F 0.47942553860420300027f
#define EPS_F   1e-8f

#define CT 256                     /* classes per block (M side) */
#define BT 128                     /* batch rows per block (N side) */
#define NCT 782                    /* 782*256 = 200192 class tiles */
#define CPAD (NCT * CT)            /* 200192 */
#define NPADROW (CPAD - C_CLS)     /* 192 zero rows -> exp(0)=1 each */
#define NBLK (NCT * 8)             /* 6256 = 8*782, bijective XCD swizzle */

typedef int   i32x4  __attribute__((ext_vector_type(4)));
typedef int   i32x8  __attribute__((ext_vector_type(8)));
typedef float f32x16 __attribute__((ext_vector_type(16)));

// ---------------- kernel 1: normalize {proto, emb} -> fp8 e4m3 ----------------
__global__ void k_norm_all8(const float* __restrict__ emb,
                            const float* __restrict__ proto,
                            unsigned char* __restrict__ ebf8,
                            unsigned char* __restrict__ pbf8) {
  int wid = threadIdx.x >> 6, lane = threadIdx.x & 63;
  int idx = (blockIdx.x << 2) + wid;
  const float* src;
  unsigned char* dst;
  if (idx < CPAD) {
    if (idx >= C_CLS) {
      *reinterpret_cast<unsigned int*>(pbf8 + (size_t)idx * D_DIM + lane * 4) = 0u;
      return;
    }
    src = proto + (size_t)idx * D_DIM;
    dst = pbf8 + (size_t)idx * D_DIM;
  } else {
    int row = idx - CPAD;
    src = emb + (size_t)row * D_DIM;
    dst = ebf8 + (size_t)row * D_DIM;
  }
  const float4 v = *reinterpret_cast<const float4*>(src + lane * 4);
  float ss = v.x * v.x + v.y * v.y + v.z * v.z + v.w * v.w;
#pragma unroll
  for (int m = 32; m >= 1; m >>= 1) ss += __shfl_xor(ss, m, 64);
  float inv = 1.0f / fmaxf(sqrtf(ss), 1e-12f);
  int packed = 0;
  packed = __builtin_amdgcn_cvt_pk_fp8_f32(v.x * inv, v.y * inv, packed, false);
  packed = __builtin_amdgcn_cvt_pk_fp8_f32(v.z * inv, v.w * inv, packed, true);
  *reinterpret_cast<int*>(dst + lane * 4) = packed;
}

// ---------------- kernel 2: swapped MX-fp8 GEMM + in-lane exp-sum -------------
// D[c, b] = mfma(protoFrag, embFrag): class dim -> in-lane rows => the
// sum_c exp() reduction needs NO per-element shuffles. Proto tile (64 KB, all
// of K) staged once -> barrier-free K-loop. Pad rows contribute exp(0)=1,
// subtracted as a constant in finalize (no masks).
__global__ __launch_bounds__(512, 4) void k_gemm_sw(
    const unsigned char* __restrict__ ebf8, const unsigned char* __restrict__ pbf8,
    float* __restrict__ sums) {
  __shared__ __align__(16) unsigned char Pls[CT * 256];   // 64 KiB, row = 256 B
  __shared__ float bsum[BT];

  const int t = threadIdx.x;
  const int lane = t & 63;
  const int rsel = lane & 31;       // row (A) / col (B) within 32
  const int h = lane >> 5;          // k-half of the 64-K window
  const int wv = t >> 6;
  const int wc = wv >> 2;           // 0..1 : 128-class strip
  const int wb = wv & 3;            // 0..3 : 32-batch strip

  int bid = (int)blockIdx.x;
  int w = (bid & 7) * NCT + (bid >> 3);   // bijective: NBLK = 8*NCT
  const int ct = w >> 3;                  // c-tiles contiguous per XCD
  const int bt = w & 7;
  const int c0 = ct * CT;
  const int b0 = bt * BT;

  // ---- prologue: stage whole proto tile (256 rows x 256 B), XOR ^(r&15) ----
#pragma unroll
  for (int j = 0; j < 8; ++j) {
    int G = j * 512 + t;            // 16-B granule index, 0..4095
    int r = G >> 4, p = G & 15;
    int lg = p ^ (r & 15);
    const unsigned char* g = pbf8 + (size_t)(c0 + r) * D_DIM + lg * 16;
    __builtin_amdgcn_global_load_lds(
        (const __attribute__((address_space(1))) unsigned int*)(const void*)g,
        (__attribute__((address_space(3))) unsigned int*)(void*)(Pls + G * 16),
        16, 0, 0);
  }
  if (t < BT) bsum[t] = 0.0f;

  f32x16 acc[4];
#pragma unroll
  for (int mi = 0; mi < 4; ++mi)
#pragma unroll
    for (int e = 0; e < 16; ++e) acc[mi][e] = 0.0f;

  asm volatile("s_waitcnt vmcnt(0)" ::: "memory");
  __syncthreads();                   // ONLY barrier before the epilogue

  // ---- barrier-free K-loop: 4 steps of K=64 ----
  const unsigned char* ebase =
      ebf8 + (size_t)(b0 + wb * 32 + rsel) * D_DIM + h * 32;
#pragma unroll
  for (int ks = 0; ks < 4; ++ks) {
    i32x4 blo = *reinterpret_cast<const i32x4*>(ebase + ks * 64);
    i32x4 bhi = *reinterpret_cast<const i32x4*>(ebase + ks * 64 + 16);
    i32x8 bf = __builtin_shufflevector(blo, bhi, 0, 1, 2, 3, 4, 5, 6, 7);
    const int g = ks * 4 + h * 2;
#pragma unroll
    for (int mi = 0; mi < 4; ++mi) {
      int r = wc * 128 + mi * 32 + rsel;
      int p0 = g ^ (r & 15), p1 = (g + 1) ^ (r & 15);
      i32x4 lo = *reinterpret_cast<const i32x4*>(Pls + r * 256 + p0 * 16);
      i32x4 hi = *reinterpret_cast<const i32x4*>(Pls + r * 256 + p1 * 16);
      i32x8 af = __builtin_shufflevector(lo, hi, 0, 1, 2, 3, 4, 5, 6, 7);
      acc[mi] = __builtin_amdgcn_mfma_scale_f32_32x32x64_f8f6f4(
          af, bf, acc[mi], 0, 0,            // cbsz=fp8, blgp=fp8
          0, 0x7F7F7F7F, 0, 0x7F7F7F7F);    // unit scales (E8M0=127)
    }
  }

  // ---- epilogue: in-lane exp-sum over all 64 class rows this lane holds ----
  float bp = 0.0f;
#pragma unroll
  for (int mi = 0; mi < 4; ++mi)
#pragma unroll
    for (int reg = 0; reg < 16; ++reg)
      bp += __expf(S_SC * acc[mi][reg]);
  bp += __shfl_xor(bp, 32, 64);      // combine the two k-half lane groups
  if (lane < 32) atomicAdd(&bsum[wb * 32 + rsel], bp);
  __syncthreads();
  if (t < BT) atomicAdd(&sums[b0 + t], bsum[t]);
}

// ---------------- kernel 3: label column + final loss -------------------------
__device__ __forceinline__ float f8tof(unsigned char u) {
  int e = (u >> 3) & 15, m = u & 7;
  float mag = e ? ldexpf((float)(8 + m), e - 10) : ldexpf((float)m, -9);
  return (u & 0x80) ? -mag : mag;
}

__global__ void k_finalize(const unsigned char* __restrict__ ebf8,
                           const unsigned char* __restrict__ pbf8,
                           const int* __restrict__ labels,
                           const float* __restrict__ sums,
                           float* __restrict__ out) {
  __shared__ float part[4];
  int wid = threadIdx.x >> 6, lane = threadIdx.x & 63;
  int b = (blockIdx.x << 2) + wid;
  int lab = labels[b];
  const unsigned char* e = ebf8 + (size_t)b * D_DIM + lane * 4;
  const unsigned char* p = pbf8 + (size_t)lab * D_DIM + lane * 4;
  unsigned int eu = *reinterpret_cast<const unsigned int*>(e);
  unsigned int pu = *reinterpret_cast<const unsigned int*>(p);
  float dot = 0.0f;
#pragma unroll
  for (int i = 0; i < 4; ++i)
    dot += f8tof((eu >> (8 * i)) & 0xff) * f8tof((pu >> (8 * i)) & 0xff);
#pragma unroll
  for (int m = 32; m >= 1; m >>= 1) dot += __shfl_xor(dot, m, 64);
  if (lane == 0) {
    float cs = dot;
    float sn = sqrtf(fmaxf(1.0f - cs * cs, EPS_F));
    sn = fminf(fmaxf(sn, EPS_F), 1.0f - EPS_F);
    float phi = cs * COS_M_F - sn * SIN_M_F;
    float sp = S_SC * phi;
    // subtract the 192 zero-pad rows' exp(0)=1 contributions
    float total = sums[b] - (float)NPADROW - __expf(S_SC * cs) + __expf(sp);
    part[wid] = logf(total) - sp;
  }
  __syncthreads();
  if (threadIdx.x == 0) {
    float s = part[0] + part[1] + part[2] + part[3];
    atomicAdd(out, s * (1.0f / (float)B_ROWS));
  }
}

// ---------------- launcher ----------------------------------------------------
extern "C" void kernel_launch(void* const* d_in, const int* in_sizes, int n_in,
                              void* d_out, int out_size, void* d_ws, size_t ws_size,
                              hipStream_t stream) {
  const float* emb    = (const float*)d_in[0];
  const int*   labels = (const int*)d_in[1];
  const float* proto  = (const float*)d_in[2];
  float* out = (float*)d_out;

  char* ws = (char*)d_ws;
  unsigned char* ebf8 = (unsigned char*)ws;                 // 262144 B
  float* sums = (float*)(ws + 262144);                      // 4096 B
  unsigned char* pbf8 = (unsigned char*)(ws + 2097152);     // CPAD*256 = 51.2 MB

  hipMemsetAsync(sums, 0, B_ROWS * sizeof(float), stream);
  hipMemsetAsync(out, 0, sizeof(float), stream);

  k_norm_all8<<<(CPAD + B_ROWS) / 4, 256, 0, stream>>>(emb, proto, ebf8, pbf8);
  k_gemm_sw<<<NBLK, 512, 0, stream>>>(ebf8, pbf8, sums);
  k_finalize<<<B_ROWS / 4, 256, 0, stream>>>(ebf8, pbf8, labels, sums, out);
}